// Round 14
// baseline (61.875 us; speedup 1.0000x reference)
//
#include <hip/hip_runtime.h>
#include <stdint.h>

// CapsuleLayer dynamic routing — round 14: W pinned via inline-asm loads.
// x: [B=256, R=1152, I=8] f32; W: [C=10, R=1152, I=8, O=16] f32
// out: v = [B, C, 1, 1, O=16] f32
//
// r12/r13: compiler sinks the 8x float4 W loads into the batch loop
// (VGPR_Count 32/28 proves W is not held), re-reading 1.5GB of W at the
// per-CU L1/L2 return-BW limit (143 GB/s/CU) = K1's entire 41us. An empty
// "+v" asm didn't stop it. This round the loads THEMSELVES are inline asm
// (global_load_dwordx4 + offset immediates): asm-defined values cannot be
// rematerialized, and an s_waitcnt vmcnt(0) asm carrying all 8 float4s as
// "+v" operands makes every FMA data-depend on the wait. W stays in 32
// VGPRs across 8 batches -> W traffic /8 -> K1 becomes write-bound (~15us).
// K2 (routing) unchanged: streams 94MB at ~5.5TB/s in ~17us.
// Fallback: round-10 fused kernel if ws too small.

#define B_ 256
#define C_ 10
#define R_ 1152
#define I_ 8
#define O_ 16
#define T_ 512
#define KPT 9            // R chunks of 128
#define NW 8
#define NITER 3

typedef float f32x4 __attribute__((ext_vector_type(4)));

__device__ __forceinline__ uint32_t bf16_rn(float f) {
    uint32_t u = __builtin_bit_cast(uint32_t, f);
    return (u + 0x7FFFu + ((u >> 16) & 1u)) >> 16;
}
__device__ __forceinline__ uint32_t pack2(float lo, float hi) {
    return bf16_rn(lo) | (bf16_rn(hi) << 16);
}
__device__ __forceinline__ float unlo(uint32_t p) {
    return __builtin_bit_cast(float, p << 16);
}
__device__ __forceinline__ float unhi(uint32_t p) {
    return __builtin_bit_cast(float, p & 0xFFFF0000u);
}

// ---------------- K1: u[b,c,r,:] = x[b,r,:] @ W[c,r,:,:]  (bf16 packed) ----
// grid 2880 = c(10) x kchunk(9) x btile(32). T=512; thread = (rl=tid>>2, oq=tid&3).
// W[c,kchunk] row-quad pinned in 32 VGPRs via asm loads, reused for 8 batches.
__global__ __launch_bounds__(T_, 3) void caps_u_kernel(
    const float* __restrict__ x,
    const float* __restrict__ w,
    uint2* __restrict__ u)
{
    const int bx  = blockIdx.x;
    const int c   = bx / 288;
    const int kc  = (bx % 288) >> 5;
    const int bt  = bx & 31;
    const int tid = threadIdx.x;
    const int oq  = tid & 3;
    const int rl  = tid >> 2;
    const int r   = kc * 128 + rl;

    // base points at W[c, r, i=0, oq*4]; the 8 i-rows are 64B apart.
    const float* wbase = w + ((size_t)c * R_ + r) * (I_ * O_) + oq * 4;
    f32x4 W0, W1, W2, W3, W4, W5, W6, W7;
    asm volatile("global_load_dwordx4 %0, %1, off"            : "=v"(W0) : "v"(wbase));
    asm volatile("global_load_dwordx4 %0, %1, off offset:64"  : "=v"(W1) : "v"(wbase));
    asm volatile("global_load_dwordx4 %0, %1, off offset:128" : "=v"(W2) : "v"(wbase));
    asm volatile("global_load_dwordx4 %0, %1, off offset:192" : "=v"(W3) : "v"(wbase));
    asm volatile("global_load_dwordx4 %0, %1, off offset:256" : "=v"(W4) : "v"(wbase));
    asm volatile("global_load_dwordx4 %0, %1, off offset:320" : "=v"(W5) : "v"(wbase));
    asm volatile("global_load_dwordx4 %0, %1, off offset:384" : "=v"(W6) : "v"(wbase));
    asm volatile("global_load_dwordx4 %0, %1, off offset:448" : "=v"(W7) : "v"(wbase));
    // All consumers data-depend on this wait (W regs are in-out operands).
    asm volatile("s_waitcnt vmcnt(0)"
                 : "+v"(W0), "+v"(W1), "+v"(W2), "+v"(W3),
                   "+v"(W4), "+v"(W5), "+v"(W6), "+v"(W7));

    #pragma unroll 4
    for (int bb = 0; bb < 8; ++bb) {
        const int b = bt * 8 + bb;
        const float4* xp = (const float4*)(x + ((size_t)b * R_ + r) * I_);
        const float4 xa = xp[0];
        const float4 xb = xp[1];
        float a0, a1, a2, a3;
        a0 = xa.x * W0[0]; a1 = xa.x * W0[1]; a2 = xa.x * W0[2]; a3 = xa.x * W0[3];
        a0 += xa.y * W1[0]; a1 += xa.y * W1[1]; a2 += xa.y * W1[2]; a3 += xa.y * W1[3];
        a0 += xa.z * W2[0]; a1 += xa.z * W2[1]; a2 += xa.z * W2[2]; a3 += xa.z * W2[3];
        a0 += xa.w * W3[0]; a1 += xa.w * W3[1]; a2 += xa.w * W3[2]; a3 += xa.w * W3[3];
        a0 += xb.x * W4[0]; a1 += xb.x * W4[1]; a2 += xb.x * W4[2]; a3 += xb.x * W4[3];
        a0 += xb.y * W5[0]; a1 += xb.y * W5[1]; a2 += xb.y * W5[2]; a3 += xb.y * W5[3];
        a0 += xb.z * W6[0]; a1 += xb.z * W6[1]; a2 += xb.z * W6[2]; a3 += xb.z * W6[3];
        a0 += xb.w * W7[0]; a1 += xb.w * W7[1]; a2 += xb.w * W7[2]; a3 += xb.w * W7[3];
        u[(((size_t)b * C_ + c) * KPT + kc) * T_ + tid] =
            make_uint2(pack2(a0, a1), pack2(a2, a3));
    }
}

// ---------------- K2: routing from materialized u ----------------
// One block per (b,c); wg = b*C + c matches u layout -> sequential reads.
// Thread loads its 9 uint2 (36 bf16 u-values) once; 3 iterations in-register.
// vsum trick: no logit registers; logit = u . (running sum of v), exp(0)=1 at it0.
__global__ __launch_bounds__(T_, 4) void caps_route_kernel(
    const uint2* __restrict__ u,
    float* __restrict__ out)
{
    const int wg   = blockIdx.x;       // = b*C + c
    const int tid  = threadIdx.x;
    const int lane = tid & 63;
    const int wid  = tid >> 6;
    const int oq   = tid & 3;

    __shared__ float sred[NW][4][4];
    __shared__ float zred[NW];
    __shared__ float vsum[O_];

    uint2 up[KPT];
    #pragma unroll
    for (int k = 0; k < KPT; ++k)
        up[k] = u[((size_t)wg * KPT + k) * T_ + tid];

    if (tid < O_) vsum[tid] = 0.f;
    __syncthreads();

    #pragma unroll
    for (int it = 0; it < NITER; ++it) {
        float4 vs = make_float4(0.f, 0.f, 0.f, 0.f);
        if (it > 0) vs = *(const float4*)&vsum[oq * 4];
        float z = 0.f, s0 = 0.f, s1 = 0.f, s2 = 0.f, s3 = 0.f;
        #pragma unroll
        for (int k = 0; k < KPT; ++k) {
            const float u0 = unlo(up[k].x);
            const float u1 = unhi(up[k].x);
            const float u2 = unlo(up[k].y);
            const float u3 = unhi(up[k].y);
            float e;
            if (it == 0) {
                e = 1.f;
            } else {
                float d = u0 * vs.x + u1 * vs.y + u2 * vs.z + u3 * vs.w;
                d += __shfl_xor(d, 1);    // quad-reduce over the 4 o-quads
                d += __shfl_xor(d, 2);
                e = __expf(d);
            }
            z += e;
            s0 += e * u0; s1 += e * u1; s2 += e * u2; s3 += e * u3;
        }
        #pragma unroll
        for (int off = 4; off <= 32; off <<= 1) {
            z  += __shfl_xor(z, off);
            s0 += __shfl_xor(s0, off);
            s1 += __shfl_xor(s1, off);
            s2 += __shfl_xor(s2, off);
            s3 += __shfl_xor(s3, off);
        }
        if (lane < 4) {   // lane == oq
            sred[wid][lane][0] = s0;
            sred[wid][lane][1] = s1;
            sred[wid][lane][2] = s2;
            sred[wid][lane][3] = s3;
            if (lane == 0) zred[wid] = z;
        }
        __syncthreads();

        if (wid == 0 && lane < O_) {
            float S = 0.f, Z = 0.f;
            #pragma unroll
            for (int wv = 0; wv < NW; ++wv) {
                S += sred[wv][lane >> 2][lane & 3];
                Z += zred[wv];
            }
            const float inv = 1.f / Z;
            const float svn = S * inv;
            float p = svn * svn;
            p += __shfl_xor(p, 1);
            p += __shfl_xor(p, 2);
            p += __shfl_xor(p, 4);
            p += __shfl_xor(p, 8);
            const float scale = sqrtf(p) / (1.f + p);
            const float vf = svn * scale;
            vsum[lane] += vf;
            if (it == NITER - 1)
                out[(size_t)wg * O_ + lane] = vf;
        }
        if (it != NITER - 1) __syncthreads();
    }
}

// ---------------- Fallback: round-10 fused kernel (proven) ----------------
#define BPB 4
#define RPP 128

__global__ __launch_bounds__(T_, 2) void capsule_fused_kernel(
    const float* __restrict__ x,
    const float* __restrict__ w,
    float* __restrict__ out)
{
    const int wg   = blockIdx.x;
    const int c    = wg >> 6;
    const int b0   = (wg & 63) * BPB;
    const int tid  = threadIdx.x;
    const int lane = tid & 63;
    const int wid  = tid >> 6;
    const int oq   = tid & 3;
    const int rl   = tid >> 2;

    __shared__ float sred[BPB][NW][4][4];
    __shared__ float zred[BPB][NW];
    __shared__ float vsum[BPB][O_];

    uint32_t up[BPB][KPT][2];

    if (tid < BPB * O_) vsum[tid >> 4][tid & 15] = 0.f;

    #pragma unroll
    for (int k = 0; k < KPT; ++k) {
        const int r = k * RPP + rl;
        const float4* wb4 = (const float4*)(w + ((size_t)c * R_ + r) * (I_ * O_));
        float4 W0 = wb4[0 * 4 + oq], W1 = wb4[1 * 4 + oq];
        float4 W2 = wb4[2 * 4 + oq], W3 = wb4[3 * 4 + oq];
        float4 W4 = wb4[4 * 4 + oq], W5 = wb4[5 * 4 + oq];
        float4 W6 = wb4[6 * 4 + oq], W7 = wb4[7 * 4 + oq];
        #pragma unroll
        for (int bb = 0; bb < BPB; ++bb) {
            const float4* xp = (const float4*)(x + ((size_t)(b0 + bb) * R_ + r) * I_);
            const float4 xa = xp[0];
            const float4 xb = xp[1];
            float a0, a1, a2, a3;
            a0 = xa.x * W0.x; a1 = xa.x * W0.y; a2 = xa.x * W0.z; a3 = xa.x * W0.w;
            a0 += xa.y * W1.x; a1 += xa.y * W1.y; a2 += xa.y * W1.z; a3 += xa.y * W1.w;
            a0 += xa.z * W2.x; a1 += xa.z * W2.y; a2 += xa.z * W2.z; a3 += xa.z * W2.w;
            a0 += xa.w * W3.x; a1 += xa.w * W3.y; a2 += xa.w * W3.z; a3 += xa.w * W3.w;
            a0 += xb.x * W4.x; a1 += xb.x * W4.y; a2 += xb.x * W4.z; a3 += xb.x * W4.w;
            a0 += xb.y * W5.x; a1 += xb.y * W5.y; a2 += xb.y * W5.z; a3 += xb.y * W5.w;
            a0 += xb.z * W6.x; a1 += xb.z * W6.y; a2 += xb.z * W6.z; a3 += xb.z * W6.w;
            a0 += xb.w * W7.x; a1 += xb.w * W7.y; a2 += xb.w * W7.z; a3 += xb.w * W7.w;
            up[bb][k][0] = pack2(a0, a1);
            up[bb][k][1] = pack2(a2, a3);
        }
    }
    __syncthreads();

    #pragma unroll
    for (int it = 0; it < NITER; ++it) {
        float zz[BPB], ss[BPB][4];
        #pragma unroll
        for (int bb = 0; bb < BPB; ++bb) {
            float4 vs = make_float4(0.f, 0.f, 0.f, 0.f);
            if (it > 0) vs = *(const float4*)&vsum[bb][oq * 4];
            float z = 0.f, s0 = 0.f, s1 = 0.f, s2 = 0.f, s3 = 0.f;
            #pragma unroll
            for (int k = 0; k < KPT; ++k) {
                const float u0 = unlo(up[bb][k][0]);
                const float u1 = unhi(up[bb][k][0]);
                const float u2 = unlo(up[bb][k][1]);
                const float u3 = unhi(up[bb][k][1]);
                float e;
                if (it == 0) {
                    e = 1.f;
                } else {
                    float d = u0 * vs.x + u1 * vs.y + u2 * vs.z + u3 * vs.w;
                    d += __shfl_xor(d, 1);
                    d += __shfl_xor(d, 2);
                    e = __expf(d);
                }
                z += e;
                s0 += e * u0; s1 += e * u1; s2 += e * u2; s3 += e * u3;
            }
            zz[bb] = z;
            ss[bb][0] = s0; ss[bb][1] = s1; ss[bb][2] = s2; ss[bb][3] = s3;
        }
        #pragma unroll
        for (int off = 4; off <= 32; off <<= 1) {
            #pragma unroll
            for (int bb = 0; bb < BPB; ++bb) {
                zz[bb] += __shfl_xor(zz[bb], off);
                ss[bb][0] += __shfl_xor(ss[bb][0], off);
                ss[bb][1] += __shfl_xor(ss[bb][1], off);
                ss[bb][2] += __shfl_xor(ss[bb][2], off);
                ss[bb][3] += __shfl_xor(ss[bb][3], off);
            }
        }
        if (lane < 4) {
            #pragma unroll
            for (int bb = 0; bb < BPB; ++bb) {
                sred[bb][wid][lane][0] = ss[bb][0];
                sred[bb][wid][lane][1] = ss[bb][1];
                sred[bb][wid][lane][2] = ss[bb][2];
                sred[bb][wid][lane][3] = ss[bb][3];
                if (lane == 0) zred[bb][wid] = zz[bb];
            }
        }
        __syncthreads();

        if (wid == 0) {
            const int bb = lane >> 4;
            const int o  = lane & 15;
            float S = 0.f, Z = 0.f;
            #pragma unroll
            for (int wv = 0; wv < NW; ++wv) {
                S += sred[bb][wv][o >> 2][o & 3];
                Z += zred[bb][wv];
            }
            const float inv = 1.f / Z;
            const float svn = S * inv;
            float p = svn * svn;
            p += __shfl_xor(p, 1);
            p += __shfl_xor(p, 2);
            p += __shfl_xor(p, 4);
            p += __shfl_xor(p, 8);
            const float scale = sqrtf(p) / (1.f + p);
            const float vf = svn * scale;
            vsum[bb][o] += vf;
            if (it == NITER - 1)
                out[((size_t)(b0 + bb) * C_ + c) * O_ + o] = vf;
        }
        if (it != NITER - 1) __syncthreads();
    }
}

extern "C" void kernel_launch(void* const* d_in, const int* in_sizes, int n_in,
                              void* d_out, int out_size, void* d_ws, size_t ws_size,
                              hipStream_t stream) {
    const float* x = (const float*)d_in[0];
    const float* w = (const float*)d_in[1];
    float* out = (float*)d_out;

    const size_t u_bytes = (size_t)B_ * C_ * KPT * T_ * 8;   // 94,371,840
    if (ws_size >= u_bytes) {
        uint2* u = (uint2*)d_ws;
        caps_u_kernel<<<dim3(C_ * KPT * 32), dim3(T_), 0, stream>>>(x, w, u);
        caps_route_kernel<<<dim3(B_ * C_), dim3(T_), 0, stream>>>(u, out);
    } else {
        capsule_fused_kernel<<<dim3(C_ * (B_ / BPB)), dim3(T_), 0, stream>>>(x, w, out);
    }
}